// Round 13
// baseline (163.113 us; speedup 1.0000x reference)
//
#include <hip/hip_runtime.h>
#include <hip/hip_fp16.h>

#define N_NODES 50000
#define N_EDGES 800000
#define NEG_SLOPE 0.2f
#define NBKT 196            // ceil(50000/256) buckets of 256 nodes
#define EBLK 200            // edge blocks (= K2 grid; <= 256 CUs so co-resident)
#define CHUNK 4000          // edges per block (EBLK*CHUNK == N_EDGES)
#define GEMM_BLOCKS 782     // ceil(50000/64)

__device__ __forceinline__ float leaky(float x) { return x >= 0.f ? x : NEG_SLOPE * x; }
__device__ __forceinline__ float readlane_f(float v, int i) {
    return __uint_as_float(__builtin_amdgcn_readlane(__float_as_uint(v), i));
}
// order-preserving float<->uint mapping for atomicMax on mixed-sign floats
__device__ __forceinline__ unsigned enc_f(float f) {
    unsigned u = __float_as_uint(f);
    return (int)u < 0 ? ~u : (u | 0x80000000u);
}
__device__ __forceinline__ float dec_f(unsigned e) {
    return __uint_as_float((int)e < 0 ? (e & 0x7FFFFFFFu) : ~e);
}

// device-scope arrive-and-wait barrier (all GRID blocks co-resident; counter
// zeroed by the PREVIOUS kernel so each graph replay starts clean)
__device__ __forceinline__ void grid_barrier(unsigned* ctr, int grid) {
    __syncthreads();
    if (threadIdx.x == 0) {
        __threadfence();   // release: prior writes visible device-wide
        __hip_atomic_fetch_add(ctr, 1u, __ATOMIC_ACQ_REL, __HIP_MEMORY_SCOPE_AGENT);
        while (__hip_atomic_load(ctr, __ATOMIC_ACQUIRE, __HIP_MEMORY_SCOPE_AGENT) < (unsigned)grid)
            __builtin_amdgcn_s_sleep(2);
        __threadfence();   // acquire: invalidate stale cached lines
    }
    __syncthreads();
}

// ---------------------------------------------------------------------------
// GEMM body (R10-identical math): h(fp16) = x@W, s_src/s_dst (f32).
// Block s_src max -> bmax[blockIdx] (layer 1) or atomicMax gmax (layer 2).
// ---------------------------------------------------------------------------
template <int K>
__device__ __forceinline__ void gemm_body(
    const float* __restrict__ x, const float* __restrict__ W,
    const float* __restrict__ a_src, const float* __restrict__ a_dst,
    __half* __restrict__ h, float* __restrict__ s_src, float* __restrict__ s_dst,
    float* __restrict__ bmax, unsigned* __restrict__ gmax_enc, int n)
{
    constexpr int BK = 32;
    __shared__ float Wl[BK][64];
    __shared__ float xt[BK][68];
    __shared__ float asl[64], adl[64];
    __shared__ float wm[4];

    int tid = threadIdx.x;
    if (tid < 64) { asl[tid] = a_src[tid]; adl[tid] = a_dst[tid]; }
    int tx = tid & 15, ty = tid >> 4;
    int row0 = blockIdx.x * 64;

    float acc[4][4] = {};

    for (int k0 = 0; k0 < K; k0 += BK) {
        __syncthreads();
        {
            const float4* Wg = (const float4*)&W[(size_t)k0 * 64];
            float4* Ws = (float4*)&Wl[0][0];
            Ws[tid]       = Wg[tid];
            Ws[tid + 256] = Wg[tid + 256];
        }
        #pragma unroll
        for (int it = 0; it < 2; ++it) {
            int idx = tid + it * 256;
            int r = idx >> 3, kq = idx & 7;
            int grow = row0 + r;
            float4 v = (grow < n) ? *(const float4*)&x[(size_t)grow * K + k0 + kq * 4]
                                  : make_float4(0.f, 0.f, 0.f, 0.f);
            xt[kq * 4 + 0][r] = v.x;
            xt[kq * 4 + 1][r] = v.y;
            xt[kq * 4 + 2][r] = v.z;
            xt[kq * 4 + 3][r] = v.w;
        }
        __syncthreads();

        #pragma unroll
        for (int kk = 0; kk < BK; ++kk) {
            float4 wv = *(const float4*)&Wl[kk][tx * 4];
            float4 xv = *(const float4*)&xt[kk][ty * 4];
            acc[0][0] += xv.x * wv.x; acc[0][1] += xv.x * wv.y; acc[0][2] += xv.x * wv.z; acc[0][3] += xv.x * wv.w;
            acc[1][0] += xv.y * wv.x; acc[1][1] += xv.y * wv.y; acc[1][2] += xv.y * wv.z; acc[1][3] += xv.y * wv.w;
            acc[2][0] += xv.z * wv.x; acc[2][1] += xv.z * wv.y; acc[2][2] += xv.z * wv.z; acc[2][3] += xv.z * wv.w;
            acc[3][0] += xv.w * wv.x; acc[3][1] += xv.w * wv.y; acc[3][2] += xv.w * wv.z; acc[3][3] += xv.w * wv.w;
        }
    }

    float wmax = -INFINITY;
    #pragma unroll
    for (int i = 0; i < 4; ++i) {
        int grow = row0 + ty * 4 + i;
        if (grow < n) {
            __half2 p0 = __floats2half2_rn(acc[i][0], acc[i][1]);
            __half2 p1 = __floats2half2_rn(acc[i][2], acc[i][3]);
            uint2 pk = make_uint2(*(unsigned*)&p0, *(unsigned*)&p1);
            *(uint2*)&h[(size_t)grow * 64 + tx * 4] = pk;
        }
        float s1 = acc[i][0] * asl[tx*4+0] + acc[i][1] * asl[tx*4+1]
                 + acc[i][2] * asl[tx*4+2] + acc[i][3] * asl[tx*4+3];
        float s2 = acc[i][0] * adl[tx*4+0] + acc[i][1] * adl[tx*4+1]
                 + acc[i][2] * adl[tx*4+2] + acc[i][3] * adl[tx*4+3];
        #pragma unroll
        for (int m = 1; m < 16; m <<= 1) {
            s1 += __shfl_xor(s1, m, 64);
            s2 += __shfl_xor(s2, m, 64);
        }
        if (grow < n) wmax = fmaxf(wmax, s1);
        if (tx == 0 && grow < n) { s_src[grow] = s1; s_dst[grow] = s2; }
    }
    wmax = fmaxf(wmax, __shfl_xor(wmax, 16, 64));
    wmax = fmaxf(wmax, __shfl_xor(wmax, 32, 64));
    if ((tid & 63) == 0) wm[tid >> 6] = wmax;
    __syncthreads();
    if (tid == 0) {
        float bm = fmaxf(fmaxf(wm[0], wm[1]), fmaxf(wm[2], wm[3]));
        if (bmax) bmax[blockIdx.x] = bm;           // layer 1: reduced in K2
        else      atomicMax(gmax_enc, enc_f(bm));  // layer 2
    }
}

// K1: gemm1 (blocks 0..781) || CSR P1 histogram (blocks 782..981).
// P1 block 0 also zeroes gmax2 + the two K2 barrier counters.
template <int K>
__global__ __launch_bounds__(256) void fused_gemm_p1(
    const float* __restrict__ x, const float* __restrict__ W,
    const float* __restrict__ a_src, const float* __restrict__ a_dst,
    __half* __restrict__ h, float* __restrict__ s_src, float* __restrict__ s_dst,
    float* __restrict__ bmax,
    const int* __restrict__ dst_, int* __restrict__ cnt,
    unsigned* __restrict__ gmaxu, int n)
{
    if (blockIdx.x >= GEMM_BLOCKS) {
        __shared__ int bins[NBKT];
        int tid = threadIdx.x, b = blockIdx.x - GEMM_BLOCKS;
        if (tid < NBKT) bins[tid] = 0;
        if (b == 0 && tid >= 253) gmaxu[tid - 252] = 0;   // gmaxu[1..3] = 0
        __syncthreads();
        int e0 = b * CHUNK;
        for (int e = e0 + tid; e < e0 + CHUNK; e += 256)
            atomicAdd(&bins[dst_[e] >> 8], 1);
        __syncthreads();
        if (tid < NBKT) cnt[b * NBKT + tid] = bins[tid];
        return;
    }
    gemm_body<K>(x, W, a_src, a_dst, h, s_src, s_dst, bmax, nullptr, n);
}

template <int K>
__global__ __launch_bounds__(256) void gat_gemm_kernel(
    const float* __restrict__ x, const float* __restrict__ W,
    const float* __restrict__ a_src, const float* __restrict__ a_dst,
    __half* __restrict__ h, float* __restrict__ s_src, float* __restrict__ s_dst,
    unsigned* __restrict__ gmax_enc, int n)
{
    gemm_body<K>(x, W, a_src, a_dst, h, s_src, s_dst, nullptr, gmax_enc, n);
}

// ---------------------------------------------------------------------------
// K2: P2 + P3 + P4 fused; 200 blocks, two grid barriers (counters gmaxu[2,3]
// zeroed by K1). Block 0 phase-1 also reduces bmax -> gmaxu[0].
// ---------------------------------------------------------------------------
__global__ __launch_bounds__(256) void p234_fused(
    int* __restrict__ cnt, int* __restrict__ btot,
    const float* __restrict__ bmax, unsigned* __restrict__ gmaxu,
    const int* __restrict__ src, const int* __restrict__ dst,
    unsigned* __restrict__ bkted,
    int* __restrict__ row_off, int* __restrict__ csr_src)
{
    __shared__ int tmp[256];
    __shared__ int aux[256];          // boffL (P3) / cur (P4)
    __shared__ int s_beg, s_end;
    __shared__ float fm[4];
    int b = blockIdx.x, tid = threadIdx.x;

    // ---- phase P2: column scan of cnt over EBLK blocks (blocks 0..195) ----
    if (b < NBKT) {
        int j = b;
        int v = (tid < EBLK) ? cnt[tid * NBKT + j] : 0;
        tmp[tid] = v; __syncthreads();
        for (int off = 1; off < 256; off <<= 1) {
            int a = (tid >= off) ? tmp[tid - off] : 0;
            __syncthreads();
            tmp[tid] += a;
            __syncthreads();
        }
        if (tid < EBLK) cnt[tid * NBKT + j] = tmp[tid] - v;   // exclusive
        if (tid == EBLK - 1) btot[j] = tmp[tid];              // bucket total
    }
    if (b == 0) {
        __syncthreads();
        float m = -INFINITY;
        for (int i = tid; i < GEMM_BLOCKS; i += 256) m = fmaxf(m, bmax[i]);
        #pragma unroll
        for (int off = 32; off; off >>= 1) m = fmaxf(m, __shfl_xor(m, off, 64));
        if ((tid & 63) == 0) fm[tid >> 6] = m;
        __syncthreads();
        if (tid == 0)
            gmaxu[0] = enc_f(fmaxf(fmaxf(fm[0], fm[1]), fmaxf(fm[2], fm[3])));
    }

    grid_barrier(&gmaxu[2], EBLK);

    // ---- phase P3: bucket edges (all 200 blocks) ----
    {
        int v = (tid < NBKT) ? btot[tid] : 0;
        tmp[tid] = v; __syncthreads();
        for (int off = 1; off < 256; off <<= 1) {
            int a = (tid >= off) ? tmp[tid - off] : 0;
            __syncthreads();
            tmp[tid] += a;
            __syncthreads();
        }
        if (tid < NBKT) aux[tid] = (tmp[tid] - v) + cnt[b * NBKT + tid];
        __syncthreads();
        int e0 = b * CHUNK;
        for (int e = e0 + tid; e < e0 + CHUNK; e += 256) {
            int d = dst[e], s = src[e];
            int pos = atomicAdd(&aux[d >> 8], 1);
            bkted[pos] = ((unsigned)(d & 255) << 16) | (unsigned)s;
        }
    }

    grid_barrier(&gmaxu[3], EBLK);

    // ---- phase P4: per-bucket CSR (blocks 0..195) ----
    if (b >= NBKT) return;
    {
        int j = b;
        int v = (tid < NBKT) ? btot[tid] : 0;
        tmp[tid] = v; __syncthreads();
        for (int off = 1; off < 256; off <<= 1) {
            int a = (tid >= off) ? tmp[tid - off] : 0;
            __syncthreads();
            tmp[tid] += a;
            __syncthreads();
        }
        if (tid == j) { s_beg = tmp[tid] - v; s_end = tmp[tid]; }
        aux[tid] = 0;
        __syncthreads();
        int beg = s_beg, end = s_end;

        for (int e = beg + tid; e < end; e += 256)
            atomicAdd(&aux[bkted[e] >> 16], 1);
        __syncthreads();
        int c = aux[tid];
        tmp[tid] = c; __syncthreads();
        for (int off = 1; off < 256; off <<= 1) {
            int a = (tid >= off) ? tmp[tid - off] : 0;
            __syncthreads();
            tmp[tid] += a;
            __syncthreads();
        }
        int offx = tmp[tid] - c;
        int node = j * 256 + tid;
        if (node < N_NODES) row_off[node] = beg + offx;
        if (node == 0) row_off[N_NODES] = N_EDGES;
        __syncthreads();
        aux[tid] = offx;
        __syncthreads();
        for (int e = beg + tid; e < end; e += 256) {
            unsigned u = bkted[e];
            int pos = beg + atomicAdd(&aux[u >> 16], 1);
            csr_src[pos] = (int)(u & 0xFFFFu);
        }
    }
}

// ---------------------------------------------------------------------------
// Fused per-node attention kernel (R10-identical). One wave per node; fp16 h
// gathers (128 B row = one line); global-max bound -> no max pass.
// ---------------------------------------------------------------------------
template <bool RELU>
__global__ __launch_bounds__(256) void gat_node_kernel(
    const int* __restrict__ row_off, const int* __restrict__ csr_src,
    const float* __restrict__ s_src, const float* __restrict__ s_dst,
    const __half* __restrict__ h, const float* __restrict__ b,
    const unsigned* __restrict__ gmax_enc, float* __restrict__ out, int n)
{
    int row = blockIdx.x * 4 + (threadIdx.x >> 6);
    int lane = threadIdx.x & 63;
    if (row >= n) return;

    int beg = row_off[row], end = row_off[row + 1];
    int deg = end - beg;
    float sd = s_dst[row];
    float m = leaky(dec_f(*gmax_enc) + sd);
    float s_self = s_src[row];
    float hself = __half2float(h[(size_t)row * 64 + lane]);
    float wself = __expf(leaky(s_self + sd) - m);

    if (deg <= 32) {
        int mysrc = row;
        if (lane < deg) mysrc = csr_src[beg + lane];
        float my_s = s_src[mysrc];
        float hv[32];
        #pragma unroll
        for (int j = 0; j < 32; ++j) {
            int s = __builtin_amdgcn_readlane(mysrc, j);
            hv[j] = __half2float(h[(size_t)s * 64 + lane]);
        }
        float mylogit = (lane < deg) ? leaky(my_s + sd) : -INFINITY;
        float w64 = __expf(mylogit - m);
        float den = w64;
        #pragma unroll
        for (int off = 32; off; off >>= 1)
            den += __shfl_xor(den, off, 64);
        den += wself;

        float acc = wself * hself;
        #pragma unroll
        for (int j = 0; j < 32; ++j)
            acc += readlane_f(w64, j) * hv[j];

        float v = acc / den + b[lane];
        if (RELU) v = fmaxf(v, 0.f);
        out[(size_t)row * 64 + lane] = v;
        return;
    }

    // generic path: deg > 32
    int   mysrc   = row;
    float mylogit = -INFINITY;
    if (lane < deg) {
        mysrc = csr_src[beg + lane];
        mylogit = leaky(s_src[mysrc] + sd);
    }
    float w64 = __expf(mylogit - m);
    float den = w64;
    #pragma unroll
    for (int off = 32; off; off >>= 1)
        den += __shfl_xor(den, off, 64);
    den += wself;

    float acc = wself * hself;
    int d0 = deg < 64 ? deg : 64;
    int nb = (d0 + 15) & ~15;
    for (int i = 0; i < nb; i += 16) {
        float hv[16];
        #pragma unroll
        for (int j = 0; j < 16; ++j) {
            int s = __builtin_amdgcn_readlane(mysrc, i + j);
            hv[j] = __half2float(h[(size_t)s * 64 + lane]);
        }
        #pragma unroll
        for (int j = 0; j < 16; ++j)
            acc += readlane_f(w64, i + j) * hv[j];
    }
    for (int e = beg + 64; e < end; ++e) {
        int s = csr_src[e];
        float w = __expf(leaky(s_src[s] + sd) - m);
        den += w;
        acc += w * __half2float(h[(size_t)s * 64 + lane]);
    }

    float v = acc / den + b[lane];
    if (RELU) v = fmaxf(v, 0.f);
    out[(size_t)row * 64 + lane] = v;
}

// ---------------------------------------------------------------------------
extern "C" void kernel_launch(void* const* d_in, const int* in_sizes, int n_in,
                              void* d_out, int out_size, void* d_ws, size_t ws_size,
                              hipStream_t stream) {
    const float* x   = (const float*)d_in[0];
    const int*   ei  = (const int*)d_in[1];
    const float* W1  = (const float*)d_in[2];
    const float* a1s = (const float*)d_in[3];
    const float* a1d = (const float*)d_in[4];
    const float* b1  = (const float*)d_in[5];
    const float* W2  = (const float*)d_in[6];
    const float* a2s = (const float*)d_in[7];
    const float* a2d = (const float*)d_in[8];
    const float* b2  = (const float*)d_in[9];
    float* out = (float*)d_out;

    const int* src = ei;
    const int* dst = ei + N_EDGES;

    char* p = (char*)d_ws;
    __half* h   = (__half*)p;           p += (size_t)N_NODES * 64 * 2;
    float* ssrc = (float*)p;            p += (size_t)N_NODES * 4;
    float* sdst = (float*)p;            p += (size_t)N_NODES * 4;
    int* row_off = (int*)p;             p += (size_t)(N_NODES + 1) * 4;
    unsigned* gmaxu = (unsigned*)p;     p += 4 * 4;   // [gmax1, gmax2, barr0, barr1]
    float* bmax = (float*)p;            p += 1024 * 4;
    int* csr_src = (int*)p;             p += (size_t)N_EDGES * 4;
    int* cnt     = (int*)p;             p += (size_t)EBLK * NBKT * 4;
    int* btot    = (int*)p;             p += (size_t)NBKT * 4;
    unsigned* bkted = (unsigned*)p;     p += (size_t)N_EDGES * 4;  // own buffer (h is live now)

    dim3 blk(256);
    int node_blocks = (N_NODES + 3) / 4;

    // K1: gemm1 (x@W1 -> h fp16, scores, bmax) || CSR P1 histogram
    fused_gemm_p1<128><<<GEMM_BLOCKS + EBLK, blk, 0, stream>>>(
        x, W1, a1s, a1d, h, ssrc, sdst, bmax, dst, cnt, gmaxu, N_NODES);
    // K2: CSR P2+P3+P4 (two grid barriers) + gmax1 reduce
    p234_fused<<<EBLK, blk, 0, stream>>>(
        cnt, btot, bmax, gmaxu, src, dst, bkted, row_off, csr_src);
    // K3: layer-1 aggregation
    gat_node_kernel<true><<<node_blocks, blk, 0, stream>>>(
        row_off, csr_src, ssrc, sdst, h, b1, gmaxu + 0, out, N_NODES);
    // K4: gemm2
    gat_gemm_kernel<64><<<GEMM_BLOCKS, blk, 0, stream>>>(
        out, W2, a2s, a2d, h, ssrc, sdst, gmaxu + 1, N_NODES);
    // K5: layer-2 aggregation
    gat_node_kernel<false><<<node_blocks, blk, 0, stream>>>(
        row_off, csr_src, ssrc, sdst, h, b2, gmaxu + 1, out, N_NODES);
}

// Round 14
// 125.785 us; speedup vs baseline: 1.2968x; 1.2968x over previous
//
#include <hip/hip_runtime.h>
#include <hip/hip_fp16.h>

#define N_NODES 50000
#define N_EDGES 800000
#define NEG_SLOPE 0.2f
#define NBKT 196            // ceil(50000/256) buckets of 256 nodes
#define EBLK 200            // edge blocks
#define CHUNK 4000          // edges per block (EBLK*CHUNK == N_EDGES)
#define GEMM_BLOCKS 782     // ceil(50000/64)

__device__ __forceinline__ float leaky(float x) { return x >= 0.f ? x : NEG_SLOPE * x; }
__device__ __forceinline__ float readlane_f(float v, int i) {
    return __uint_as_float(__builtin_amdgcn_readlane(__float_as_uint(v), i));
}
// order-preserving float<->uint mapping for atomicMax on mixed-sign floats
__device__ __forceinline__ unsigned enc_f(float f) {
    unsigned u = __float_as_uint(f);
    return (int)u < 0 ? ~u : (u | 0x80000000u);
}
__device__ __forceinline__ float dec_f(unsigned e) {
    return __uint_as_float((int)e < 0 ? (e & 0x7FFFFFFFu) : ~e);
}

// ---------------------------------------------------------------------------
// GEMM body (R10-identical math): h(fp16) = x@W, s_src/s_dst (f32).
// Block s_src max -> bmax[blockIdx] (layer 1) or atomicMax gmax (layer 2).
// ---------------------------------------------------------------------------
template <int K>
__device__ __forceinline__ void gemm_body(
    const float* __restrict__ x, const float* __restrict__ W,
    const float* __restrict__ a_src, const float* __restrict__ a_dst,
    __half* __restrict__ h, float* __restrict__ s_src, float* __restrict__ s_dst,
    float* __restrict__ bmax, unsigned* __restrict__ gmax_enc, int n)
{
    constexpr int BK = 32;
    __shared__ float Wl[BK][64];
    __shared__ float xt[BK][68];
    __shared__ float asl[64], adl[64];
    __shared__ float wm[4];

    int tid = threadIdx.x;
    if (tid < 64) { asl[tid] = a_src[tid]; adl[tid] = a_dst[tid]; }
    int tx = tid & 15, ty = tid >> 4;
    int row0 = blockIdx.x * 64;

    float acc[4][4] = {};

    for (int k0 = 0; k0 < K; k0 += BK) {
        __syncthreads();
        {
            const float4* Wg = (const float4*)&W[(size_t)k0 * 64];
            float4* Ws = (float4*)&Wl[0][0];
            Ws[tid]       = Wg[tid];
            Ws[tid + 256] = Wg[tid + 256];
        }
        #pragma unroll
        for (int it = 0; it < 2; ++it) {
            int idx = tid + it * 256;
            int r = idx >> 3, kq = idx & 7;
            int grow = row0 + r;
            float4 v = (grow < n) ? *(const float4*)&x[(size_t)grow * K + k0 + kq * 4]
                                  : make_float4(0.f, 0.f, 0.f, 0.f);
            xt[kq * 4 + 0][r] = v.x;
            xt[kq * 4 + 1][r] = v.y;
            xt[kq * 4 + 2][r] = v.z;
            xt[kq * 4 + 3][r] = v.w;
        }
        __syncthreads();

        #pragma unroll
        for (int kk = 0; kk < BK; ++kk) {
            float4 wv = *(const float4*)&Wl[kk][tx * 4];
            float4 xv = *(const float4*)&xt[kk][ty * 4];
            acc[0][0] += xv.x * wv.x; acc[0][1] += xv.x * wv.y; acc[0][2] += xv.x * wv.z; acc[0][3] += xv.x * wv.w;
            acc[1][0] += xv.y * wv.x; acc[1][1] += xv.y * wv.y; acc[1][2] += xv.y * wv.z; acc[1][3] += xv.y * wv.w;
            acc[2][0] += xv.z * wv.x; acc[2][1] += xv.z * wv.y; acc[2][2] += xv.z * wv.z; acc[2][3] += xv.z * wv.w;
            acc[3][0] += xv.w * wv.x; acc[3][1] += xv.w * wv.y; acc[3][2] += xv.w * wv.z; acc[3][3] += xv.w * wv.w;
        }
    }

    float wmax = -INFINITY;
    #pragma unroll
    for (int i = 0; i < 4; ++i) {
        int grow = row0 + ty * 4 + i;
        if (grow < n) {
            __half2 p0 = __floats2half2_rn(acc[i][0], acc[i][1]);
            __half2 p1 = __floats2half2_rn(acc[i][2], acc[i][3]);
            uint2 pk = make_uint2(*(unsigned*)&p0, *(unsigned*)&p1);
            *(uint2*)&h[(size_t)grow * 64 + tx * 4] = pk;
        }
        float s1 = acc[i][0] * asl[tx*4+0] + acc[i][1] * asl[tx*4+1]
                 + acc[i][2] * asl[tx*4+2] + acc[i][3] * asl[tx*4+3];
        float s2 = acc[i][0] * adl[tx*4+0] + acc[i][1] * adl[tx*4+1]
                 + acc[i][2] * adl[tx*4+2] + acc[i][3] * adl[tx*4+3];
        #pragma unroll
        for (int m = 1; m < 16; m <<= 1) {
            s1 += __shfl_xor(s1, m, 64);
            s2 += __shfl_xor(s2, m, 64);
        }
        if (grow < n) wmax = fmaxf(wmax, s1);
        if (tx == 0 && grow < n) { s_src[grow] = s1; s_dst[grow] = s2; }
    }
    wmax = fmaxf(wmax, __shfl_xor(wmax, 16, 64));
    wmax = fmaxf(wmax, __shfl_xor(wmax, 32, 64));
    if ((tid & 63) == 0) wm[tid >> 6] = wmax;
    __syncthreads();
    if (tid == 0) {
        float bm = fmaxf(fmaxf(wm[0], wm[1]), fmaxf(wm[2], wm[3]));
        if (bmax) bmax[blockIdx.x] = bm;           // layer 1: reduced in K2
        else      atomicMax(gmax_enc, enc_f(bm));  // layer 2
    }
}

// K1: gemm1 (blocks 0..781) || CSR P1 histogram (blocks 782..981).
template <int K>
__global__ __launch_bounds__(256) void fused_gemm_p1(
    const float* __restrict__ x, const float* __restrict__ W,
    const float* __restrict__ a_src, const float* __restrict__ a_dst,
    __half* __restrict__ h, float* __restrict__ s_src, float* __restrict__ s_dst,
    float* __restrict__ bmax,
    const int* __restrict__ dst_, int* __restrict__ cnt, int n)
{
    if (blockIdx.x >= GEMM_BLOCKS) {
        __shared__ int bins[NBKT];
        int tid = threadIdx.x, b = blockIdx.x - GEMM_BLOCKS;
        if (tid < NBKT) bins[tid] = 0;
        __syncthreads();
        int e0 = b * CHUNK;
        for (int e = e0 + tid; e < e0 + CHUNK; e += 256)
            atomicAdd(&bins[dst_[e] >> 8], 1);
        __syncthreads();
        if (tid < NBKT) cnt[b * NBKT + tid] = bins[tid];
        return;
    }
    gemm_body<K>(x, W, a_src, a_dst, h, s_src, s_dst, bmax, nullptr, n);
}

template <int K>
__global__ __launch_bounds__(256) void gat_gemm_kernel(
    const float* __restrict__ x, const float* __restrict__ W,
    const float* __restrict__ a_src, const float* __restrict__ a_dst,
    __half* __restrict__ h, float* __restrict__ s_src, float* __restrict__ s_dst,
    unsigned* __restrict__ gmax_enc, int n)
{
    gemm_body<K>(x, W, a_src, a_dst, h, s_src, s_dst, nullptr, gmax_enc, n);
}

// ---------------------------------------------------------------------------
// K2: P2+P3 fused WITHOUT barriers — each block redundantly computes from the
// raw cnt matrix: bucket totals (column sums), bucket bases (LDS scan), and
// its own per-bucket offset (partial column sums b'<b). 200 coalesced 784 B
// loads per block, all L2-hot. Block 0 also writes btot, reduces bmax->gmax1,
// zeroes gmax2.
// ---------------------------------------------------------------------------
__global__ __launch_bounds__(256) void p23_fused(
    const int* __restrict__ cnt, int* __restrict__ btot,
    const float* __restrict__ bmax, unsigned* __restrict__ gmaxu,
    const int* __restrict__ src, const int* __restrict__ dst,
    unsigned* __restrict__ bkted)
{
    __shared__ int tmp[256];
    __shared__ int boffL[NBKT];
    __shared__ float fm[4];
    int b = blockIdx.x, tid = threadIdx.x;

    // column sums + my partial sum (coalesced: consecutive tid -> consecutive j)
    int total = 0, myoff = 0;
    if (tid < NBKT) {
        for (int bp = 0; bp < EBLK; ++bp) {
            int v = cnt[bp * NBKT + tid];
            total += v;
            if (bp < b) myoff += v;
        }
    }
    tmp[tid] = (tid < NBKT) ? total : 0;
    __syncthreads();
    for (int off = 1; off < 256; off <<= 1) {
        int a = (tid >= off) ? tmp[tid - off] : 0;
        __syncthreads();
        tmp[tid] += a;
        __syncthreads();
    }
    if (tid < NBKT) {
        int base = tmp[tid] - total;          // exclusive scan of totals
        boffL[tid] = base + myoff;
        if (b == 0) btot[tid] = total;
    }
    __syncthreads();

    // scatter this block's edges into bucket regions (LDS cursors only)
    int e0 = b * CHUNK;
    for (int e = e0 + tid; e < e0 + CHUNK; e += 256) {
        int d = dst[e], s = src[e];
        int pos = atomicAdd(&boffL[d >> 8], 1);
        bkted[pos] = ((unsigned)(d & 255) << 16) | (unsigned)s;
    }

    // block 0: reduce bmax -> gmax1, zero gmax2 (for gemm2's atomicMax)
    if (b == 0) {
        float m = -INFINITY;
        for (int i = tid; i < GEMM_BLOCKS; i += 256) m = fmaxf(m, bmax[i]);
        #pragma unroll
        for (int off = 32; off; off >>= 1) m = fmaxf(m, __shfl_xor(m, off, 64));
        if ((tid & 63) == 0) fm[tid >> 6] = m;
        __syncthreads();
        if (tid == 0) {
            gmaxu[0] = enc_f(fmaxf(fmaxf(fm[0], fm[1]), fmaxf(fm[2], fm[3])));
            gmaxu[1] = 0;
        }
    }
}

// P4: one block per bucket; per-node count/scan/scatter in LDS. (R10-identical)
__global__ __launch_bounds__(256) void p4_csr(
    const unsigned* __restrict__ bkted, const int* __restrict__ btot,
    int* __restrict__ row_off, int* __restrict__ csr_src)
{
    __shared__ int tmp[256];
    __shared__ int cur[256];
    __shared__ int s_beg, s_end;
    int j = blockIdx.x, tid = threadIdx.x;
    int v = (tid < NBKT) ? btot[tid] : 0;
    tmp[tid] = v; __syncthreads();
    for (int off = 1; off < 256; off <<= 1) {
        int a = (tid >= off) ? tmp[tid - off] : 0;
        __syncthreads();
        tmp[tid] += a;
        __syncthreads();
    }
    if (tid == j) { s_beg = tmp[tid] - v; s_end = tmp[tid]; }
    cur[tid] = 0;
    __syncthreads();
    int beg = s_beg, end = s_end;

    for (int e = beg + tid; e < end; e += 256)
        atomicAdd(&cur[bkted[e] >> 16], 1);
    __syncthreads();
    int c = cur[tid];
    tmp[tid] = c; __syncthreads();
    for (int off = 1; off < 256; off <<= 1) {
        int a = (tid >= off) ? tmp[tid - off] : 0;
        __syncthreads();
        tmp[tid] += a;
        __syncthreads();
    }
    int offx = tmp[tid] - c;
    int node = j * 256 + tid;
    if (node < N_NODES) row_off[node] = beg + offx;
    if (node == 0) row_off[N_NODES] = N_EDGES;
    __syncthreads();
    cur[tid] = offx;
    __syncthreads();
    for (int e = beg + tid; e < end; e += 256) {
        unsigned u = bkted[e];
        int pos = beg + atomicAdd(&cur[u >> 16], 1);
        csr_src[pos] = (int)(u & 0xFFFFu);
    }
}

// ---------------------------------------------------------------------------
// Fused per-node attention kernel (R10-identical). One wave per node; fp16 h
// gathers (128 B row = one line); global-max bound -> no max pass.
// ---------------------------------------------------------------------------
template <bool RELU>
__global__ __launch_bounds__(256) void gat_node_kernel(
    const int* __restrict__ row_off, const int* __restrict__ csr_src,
    const float* __restrict__ s_src, const float* __restrict__ s_dst,
    const __half* __restrict__ h, const float* __restrict__ b,
    const unsigned* __restrict__ gmax_enc, float* __restrict__ out, int n)
{
    int row = blockIdx.x * 4 + (threadIdx.x >> 6);
    int lane = threadIdx.x & 63;
    if (row >= n) return;

    int beg = row_off[row], end = row_off[row + 1];
    int deg = end - beg;
    float sd = s_dst[row];
    float m = leaky(dec_f(*gmax_enc) + sd);
    float s_self = s_src[row];
    float hself = __half2float(h[(size_t)row * 64 + lane]);
    float wself = __expf(leaky(s_self + sd) - m);

    if (deg <= 32) {
        int mysrc = row;
        if (lane < deg) mysrc = csr_src[beg + lane];
        float my_s = s_src[mysrc];
        float hv[32];
        #pragma unroll
        for (int j = 0; j < 32; ++j) {
            int s = __builtin_amdgcn_readlane(mysrc, j);
            hv[j] = __half2float(h[(size_t)s * 64 + lane]);
        }
        float mylogit = (lane < deg) ? leaky(my_s + sd) : -INFINITY;
        float w64 = __expf(mylogit - m);
        float den = w64;
        #pragma unroll
        for (int off = 32; off; off >>= 1)
            den += __shfl_xor(den, off, 64);
        den += wself;

        float acc = wself * hself;
        #pragma unroll
        for (int j = 0; j < 32; ++j)
            acc += readlane_f(w64, j) * hv[j];

        float v = acc / den + b[lane];
        if (RELU) v = fmaxf(v, 0.f);
        out[(size_t)row * 64 + lane] = v;
        return;
    }

    // generic path: deg > 32
    int   mysrc   = row;
    float mylogit = -INFINITY;
    if (lane < deg) {
        mysrc = csr_src[beg + lane];
        mylogit = leaky(s_src[mysrc] + sd);
    }
    float w64 = __expf(mylogit - m);
    float den = w64;
    #pragma unroll
    for (int off = 32; off; off >>= 1)
        den += __shfl_xor(den, off, 64);
    den += wself;

    float acc = wself * hself;
    int d0 = deg < 64 ? deg : 64;
    int nb = (d0 + 15) & ~15;
    for (int i = 0; i < nb; i += 16) {
        float hv[16];
        #pragma unroll
        for (int j = 0; j < 16; ++j) {
            int s = __builtin_amdgcn_readlane(mysrc, i + j);
            hv[j] = __half2float(h[(size_t)s * 64 + lane]);
        }
        #pragma unroll
        for (int j = 0; j < 16; ++j)
            acc += readlane_f(w64, i + j) * hv[j];
    }
    for (int e = beg + 64; e < end; ++e) {
        int s = csr_src[e];
        float w = __expf(leaky(s_src[s] + sd) - m);
        den += w;
        acc += w * __half2float(h[(size_t)s * 64 + lane]);
    }

    float v = acc / den + b[lane];
    if (RELU) v = fmaxf(v, 0.f);
    out[(size_t)row * 64 + lane] = v;
}

// ---------------------------------------------------------------------------
extern "C" void kernel_launch(void* const* d_in, const int* in_sizes, int n_in,
                              void* d_out, int out_size, void* d_ws, size_t ws_size,
                              hipStream_t stream) {
    const float* x   = (const float*)d_in[0];
    const int*   ei  = (const int*)d_in[1];
    const float* W1  = (const float*)d_in[2];
    const float* a1s = (const float*)d_in[3];
    const float* a1d = (const float*)d_in[4];
    const float* b1  = (const float*)d_in[5];
    const float* W2  = (const float*)d_in[6];
    const float* a2s = (const float*)d_in[7];
    const float* a2d = (const float*)d_in[8];
    const float* b2  = (const float*)d_in[9];
    float* out = (float*)d_out;

    const int* src = ei;
    const int* dst = ei + N_EDGES;

    char* p = (char*)d_ws;
    __half* h   = (__half*)p;           p += (size_t)N_NODES * 64 * 2;
    float* ssrc = (float*)p;            p += (size_t)N_NODES * 4;
    float* sdst = (float*)p;            p += (size_t)N_NODES * 4;
    int* row_off = (int*)p;             p += (size_t)(N_NODES + 1) * 4;
    unsigned* gmaxu = (unsigned*)p;     p += 4 * 4;   // [gmax1, gmax2]
    float* bmax = (float*)p;            p += 1024 * 4;
    int* csr_src = (int*)p;             p += (size_t)N_EDGES * 4;
    int* cnt     = (int*)p;             p += (size_t)EBLK * NBKT * 4;
    int* btot    = (int*)p;             p += (size_t)NBKT * 4;
    unsigned* bkted = (unsigned*)p;     p += (size_t)N_EDGES * 4;  // own buffer (h live)

    dim3 blk(256);
    int node_blocks = (N_NODES + 3) / 4;

    // K1: gemm1 (x@W1 -> h fp16, scores, bmax) || CSR P1 histogram
    fused_gemm_p1<128><<<GEMM_BLOCKS + EBLK, blk, 0, stream>>>(
        x, W1, a1s, a1d, h, ssrc, sdst, bmax, dst, cnt, N_NODES);
    // K2: CSR P2+P3 fused (redundant scans, no barrier) + gmax1 reduce
    p23_fused<<<EBLK, blk, 0, stream>>>(cnt, btot, bmax, gmaxu, src, dst, bkted);
    // K3: CSR P4
    p4_csr<<<NBKT, blk, 0, stream>>>(bkted, btot, row_off, csr_src);
    // K4: layer-1 aggregation
    gat_node_kernel<true><<<node_blocks, blk, 0, stream>>>(
        row_off, csr_src, ssrc, sdst, h, b1, gmaxu + 0, out, N_NODES);
    // K5: gemm2
    gat_gemm_kernel<64><<<GEMM_BLOCKS, blk, 0, stream>>>(
        out, W2, a2s, a2d, h, ssrc, sdst, gmaxu + 1, N_NODES);
    // K6: layer-2 aggregation
    gat_node_kernel<false><<<node_blocks, blk, 0, stream>>>(
        row_off, csr_src, ssrc, sdst, h, b2, gmaxu + 1, out, N_NODES);
}